// Round 1
// baseline (203.105 us; speedup 1.0000x reference)
//
#include <hip/hip_runtime.h>

// ShiftedWindowAttention3d on MI355X (gfx950).
// Geometry: x[1,16,56,56,192], WIN=(8,7,7), SHIFT=(4,3,3) -> no pad, shifted.
// 128 windows x 392 tokens, 6 heads x hd=32.
// Pipeline: wconv -> rpb table -> QKV gemm (gather+mfma) -> fused attn -> proj gemm (scatter).
// Workspace needed: ~81.3 MB.

typedef _Float16 f16;
typedef __attribute__((ext_vector_type(8))) _Float16 f16x8;
typedef __attribute__((ext_vector_type(4))) _Float16 f16x4;
typedef __attribute__((ext_vector_type(4))) float f32x4;

#define MFMA16(a, b, c) __builtin_amdgcn_mfma_f32_16x16x32_f16((a), (b), (c), 0, 0, 0)

#define HEADS 6
#define NWIN 128
#define NTOK 392
#define TOKENS (NWIN * NTOK)   // 50176
#define CDIM 192

__device__ inline f16x8 f16x8_zero() {
    f16x8 v = {(f16)0.f,(f16)0.f,(f16)0.f,(f16)0.f,(f16)0.f,(f16)0.f,(f16)0.f,(f16)0.f};
    return v;
}

// ---------------- kernel 0a: weights fp32 -> f16 ----------------
__global__ __launch_bounds__(256) void wconv_kernel(
    const float* __restrict__ wqkv, const float* __restrict__ wproj,
    f16* __restrict__ wqkv_h, f16* __restrict__ wproj_h)
{
    int i = blockIdx.x * 256 + threadIdx.x;
    if (i < 576 * 192) wqkv_h[i] = (f16)wqkv[i];
    if (i < 192 * 192) wproj_h[i] = (f16)wproj[i];
}

// ---------------- kernel 0b: relative position bias table [6][400][400] f32 ----------------
__global__ __launch_bounds__(256) void rpb_kernel(
    const float* __restrict__ tbl, float* __restrict__ rpb)
{
    int i = blockIdx.x * 256 + threadIdx.x;
    if (i >= 6 * 400 * 400) return;
    int h = i / 160000;
    int r = i - h * 160000;
    int n = r / 400;
    int m = r - n * 400;
    float v;
    if (n < NTOK && m < NTOK) {
        int td = n / 49, t2 = n - td * 49, th = t2 / 7, tw = t2 - th * 7;
        int md = m / 49, m2 = m - md * 49, mh = m2 / 7, mw = m2 - mh * 7;
        int idx = ((td - md + 7) * 13 + (th - mh + 6)) * 13 + (tw - mw + 6);
        v = tbl[idx * 6 + h];
    } else {
        v = -1e30f;  // padded rows/cols vanish in softmax (no NaN: -1e30 - -1e30 = 0)
    }
    rpb[i] = v;
}

// ---------------- kernel 1: gather(roll+window) + QKV GEMM ----------------
// grid (784, 3): 64-token tile x 192-output tile. bn==0 -> Q, 192 -> K, 384 -> V.
__global__ __launch_bounds__(256, 2) void qkv_kernel(
    const float* __restrict__ x, const f16* __restrict__ wq,
    const float* __restrict__ bq,
    f16* __restrict__ q_ws, f16* __restrict__ k_ws, f16* __restrict__ v_ws)
{
    __shared__ __align__(16) f16 a_lds[64 * 256];  // 64 rows x 512B (swizzled), 32 KB
    const int tid = threadIdx.x;
    const int bm = blockIdx.x * 64;
    const int bn = blockIdx.y * 192;

    // stage A tile: gather x (roll + window partition), f32 -> f16, XOR-swizzled LDS
    for (int i = tid; i < 64 * 24; i += 256) {
        int row = i / 24, c = i - row * 24;       // c = 8-channel chunk
        int tok = bm + row;
        int win = tok / NTOK, nloc = tok - win * NTOK;
        int td = nloc / 49, r2 = nloc - td * 49, th = r2 / 7, tw = r2 - th * 7;
        int wd = win >> 6, wh = (win >> 3) & 7, ww = win & 7;
        int d = (wd * 8 + td + 4) & 15;
        int hh = wh * 7 + th + 3; if (hh >= 56) hh -= 56;
        int wco = ww * 7 + tw + 3; if (wco >= 56) wco -= 56;
        const float* src = x + ((d * 56 + hh) * 56 + wco) * CDIM + c * 8;
        const float4 u0 = *(const float4*)(src);
        const float4 u1 = *(const float4*)(src + 4);
        f16x8 v;
        v[0] = (f16)u0.x; v[1] = (f16)u0.y; v[2] = (f16)u0.z; v[3] = (f16)u0.w;
        v[4] = (f16)u1.x; v[5] = (f16)u1.y; v[6] = (f16)u1.z; v[7] = (f16)u1.w;
        *(f16x8*)&a_lds[row * 256 + ((c ^ (row & 7)) << 3)] = v;
    }
    __syncthreads();

    const int lane = tid & 63, wv = tid >> 6;
    const int l15 = lane & 15, g = lane >> 4;
    const int m0 = (wv & 1) * 32, n0 = (wv >> 1) * 96;

    const f32x4 z4 = {0.f, 0.f, 0.f, 0.f};
    f32x4 acc[2][6];
    #pragma unroll
    for (int mi = 0; mi < 2; mi++)
        #pragma unroll
        for (int ni = 0; ni < 6; ni++) acc[mi][ni] = z4;

    #pragma unroll
    for (int kk = 0; kk < 6; kk++) {
        f16x8 af[2];
        #pragma unroll
        for (int mi = 0; mi < 2; mi++) {
            int row = m0 + mi * 16 + l15;
            af[mi] = *(const f16x8*)&a_lds[row * 256 + (((kk * 4 + g) ^ (row & 7)) << 3)];
        }
        #pragma unroll
        for (int ni = 0; ni < 6; ni++) {
            const f16x8 bf = *(const f16x8*)&wq[(bn + n0 + ni * 16 + l15) * CDIM + kk * 32 + g * 8];
            #pragma unroll
            for (int mi = 0; mi < 2; mi++)
                acc[mi][ni] = MFMA16(af[mi], bf, acc[mi][ni]);
        }
    }

    // epilogue: bias, split q/k/v; q pre-scaled; v written transposed [head][hd][tok]
    #pragma unroll
    for (int mi = 0; mi < 2; mi++) {
        const int tok0 = bm + m0 + mi * 16 + g * 4;
        const int win = tok0 / NTOK, nloc0 = tok0 - win * NTOK;
        #pragma unroll
        for (int ni = 0; ni < 6; ni++) {
            const int n = bn + n0 + ni * 16 + l15;
            const float bias = bq[n];
            if (bn == 0) {
                const int head = n >> 5, hd = n & 31;
                f16* dst = q_ws + ((win * HEADS + head) * NTOK + nloc0) * 32 + hd;
                #pragma unroll
                for (int j = 0; j < 4; j++)
                    dst[j * 32] = (f16)((acc[mi][ni][j] + bias) * 0.17677669529663687f);
            } else if (bn == 192) {
                const int cc = n - 192, head = cc >> 5, hd = cc & 31;
                f16* dst = k_ws + ((win * HEADS + head) * NTOK + nloc0) * 32 + hd;
                #pragma unroll
                for (int j = 0; j < 4; j++)
                    dst[j * 32] = (f16)(acc[mi][ni][j] + bias);
            } else {
                const int cc = n - 384, head = cc >> 5, hd = cc & 31;
                f16x4 pk;
                #pragma unroll
                for (int j = 0; j < 4; j++) pk[j] = (f16)(acc[mi][ni][j] + bias);
                *(f16x4*)(v_ws + ((win * HEADS + head) * 32 + hd) * NTOK + nloc0) = pk;
            }
        }
    }
}

// ---------------- kernel 2: fused window attention ----------------
// grid 768 = 128 windows x 6 heads, 256 threads (4 waves).
// K,V staged fragment-major in LDS (conflict-free b128 reads). Full-row softmax in regs.
__global__ __launch_bounds__(256, 2) void attn_kernel(
    const f16* __restrict__ q_ws, const f16* __restrict__ k_ws,
    const f16* __restrict__ v_ws, const float* __restrict__ rpb,
    f16* __restrict__ o_ws)
{
    __shared__ __align__(16) f16 k_lds[25 * 512];    // 25 K-tiles, frag-major, 25.0 KB
    __shared__ __align__(16) f16 v_lds[13 * 1024];   // 13 V-blocks, frag-major, 26 KB
    __shared__ __align__(16) f16 p_scr[4][512];      // per-wave P transpose scratch
    __shared__ unsigned char region[400];

    const int tid = threadIdx.x;
    const int bid = blockIdx.x;
    const int win = bid / 6, head = bid - win * 6;
    const int wd = win >> 6, wh = (win >> 3) & 7, ww = win & 7;
    const f16* kb = k_ws + (win * HEADS + head) * NTOK * 32;
    const f16* vb = v_ws + (win * HEADS + head) * 32 * NTOK;
    const f16* qb = q_ws + (win * HEADS + head) * NTOK * 32;

    // shift-mask region id per token (only last window in each dim is mixed)
    for (int i = tid; i < 400; i += 256) {
        unsigned char rr = 0;
        if (i < NTOK) {
            int td = i / 49, r2 = i - td * 49, th = r2 / 7, tw = r2 - th * 7;
            int rd = (wd == 1) ? (td < 4 ? 1 : 2) : 0;
            int rh = (wh == 7) ? (th < 4 ? 1 : 2) : 0;
            int rw = (ww == 7) ? (tw < 4 ? 1 : 2) : 0;
            rr = (unsigned char)(rd * 9 + rh * 3 + rw);
        }
        region[i] = rr;
    }
    // K: tile t, lane l holds K[t*16 + (l&15)][(l>>4)*8 .. +8] at lds offset (t*64+l)*16B
    for (int i = tid; i < 1600; i += 256) {
        const int tok = ((i >> 6) << 4) | (i & 15);
        const int gg = (i >> 4) & 3;
        f16x8 v = f16x8_zero();
        if (tok < NTOK) v = *(const f16x8*)(kb + tok * 32 + gg * 8);
        *(f16x8*)&k_lds[i * 8] = v;
    }
    // V: block tb, half nt, lane l holds V^T[nt*16+(l&15)][tb*32+(l>>4)*8 .. +8]
    for (int i = tid; i < 1664; i += 256) {
        const int tb = i >> 7, rest = i & 127;
        const int hd = ((rest >> 6) << 4) | (rest & 15);
        const int gg = (rest >> 4) & 3;
        const int tok0 = tb * 32 + gg * 8;
        f16x8 v = f16x8_zero();
        if (tok0 < NTOK) v = *(const f16x8*)(vb + hd * NTOK + tok0);
        *(f16x8*)&v_lds[i * 8] = v;
    }
    __syncthreads();

    const int lane = tid & 63, wv = tid >> 6, l15 = lane & 15, g = lane >> 4;
    f16* scr = &p_scr[wv][0];
    const f32x4 z4 = {0.f, 0.f, 0.f, 0.f};

    for (int strip = wv; strip < 25; strip += 4) {
        const int q0 = strip * 16;
        int qr = q0 + l15; if (qr > NTOK - 1) qr = NTOK - 1;  // clamp pad rows
        const f16x8 qf = *(const f16x8*)(qb + qr * 32 + g * 8);

        // S = Q K^T : 25 tiles of 16 cols, K-dim = hd = 32 (single mfma each)
        f32x4 acc[25];
        #pragma unroll
        for (int t = 0; t < 25; t++) {
            const f16x8 kf = *(const f16x8*)&k_lds[t * 512 + lane * 8];
            acc[t] = MFMA16(qf, kf, z4);
        }

        // + rel-pos bias (padded entries = -1e30) + shift mask
        const int rowb = q0 + g * 4;
        unsigned char rrow[4];
        #pragma unroll
        for (int j = 0; j < 4; j++) rrow[j] = region[rowb + j];
        const float* rpbrow = rpb + (head * 400 + rowb) * 400;
        #pragma unroll
        for (int t = 0; t < 25; t++) {
            const int col = t * 16 + l15;
            const unsigned char rc = region[col];
            #pragma unroll
            for (int j = 0; j < 4; j++) {
                const float bias = rpbrow[j * 400 + col];
                acc[t][j] += (rc == rrow[j]) ? bias : (bias - 100.0f);
            }
        }

        // softmax over 400 cols: per-lane reduce over tiles + shfl_xor over 16 lanes
        float mx[4], rinv[4];
        #pragma unroll
        for (int j = 0; j < 4; j++) {
            float m = acc[0][j];
            #pragma unroll
            for (int t = 1; t < 25; t++) m = fmaxf(m, acc[t][j]);
            m = fmaxf(m, __shfl_xor(m, 1));
            m = fmaxf(m, __shfl_xor(m, 2));
            m = fmaxf(m, __shfl_xor(m, 4));
            m = fmaxf(m, __shfl_xor(m, 8));
            mx[j] = m;
        }
        #pragma unroll
        for (int t = 0; t < 25; t++) {
            #pragma unroll
            for (int j = 0; j < 4; j++) acc[t][j] = __expf(acc[t][j] - mx[j]);
        }
        #pragma unroll
        for (int j = 0; j < 4; j++) {
            float s = 0.f;
            #pragma unroll
            for (int t = 0; t < 25; t++) s += acc[t][j];
            s += __shfl_xor(s, 1);
            s += __shfl_xor(s, 2);
            s += __shfl_xor(s, 4);
            s += __shfl_xor(s, 8);
            rinv[j] = 1.0f / s;
        }

        // O = P V (normalize at the end): transpose P 2 tiles at a time via wave-local scratch
        f32x4 oacc[2] = {z4, z4};
        #pragma unroll
        for (int tb = 0; tb < 13; tb++) {
            #pragma unroll
            for (int half = 0; half < 2; half++) {
                const int t = tb * 2 + half;
                const int tok32 = half * 16 + l15;
                const int wbase = (tok32 >> 3) * 128 + (tok32 & 7);
                #pragma unroll
                for (int j = 0; j < 4; j++) {
                    const f16 pv = (t < 25) ? (f16)acc[t][j] : (f16)0.f;
                    scr[(g * 4 + j) * 8 + wbase] = pv;
                }
            }
            const f16x8 pf = *(const f16x8*)&scr[lane * 8];
            #pragma unroll
            for (int nt = 0; nt < 2; nt++) {
                const f16x8 vf = *(const f16x8*)&v_lds[tb * 1024 + nt * 512 + lane * 8];
                oacc[nt] = MFMA16(pf, vf, oacc[nt]);
            }
        }

        #pragma unroll
        for (int j = 0; j < 4; j++) {
            const int row = rowb + j;
            if (row < NTOK) {
                f16* dst = o_ws + (win * NTOK + row) * CDIM + head * 32;
                dst[l15]      = (f16)(oacc[0][j] * rinv[j]);
                dst[16 + l15] = (f16)(oacc[1][j] * rinv[j]);
            }
        }
    }
}

// ---------------- kernel 3: proj GEMM + window-reverse/roll scatter ----------------
// grid 784: 64-token tile x full 192 outputs.
__global__ __launch_bounds__(256, 2) void proj_kernel(
    const f16* __restrict__ o_ws, const f16* __restrict__ wp,
    const float* __restrict__ bp, float* __restrict__ out)
{
    __shared__ __align__(16) f16 a_lds[64 * 256];
    const int tid = threadIdx.x;
    const int bm = blockIdx.x * 64;
    for (int i = tid; i < 64 * 24; i += 256) {
        int row = i / 24, c = i - row * 24;
        f16x8 v = *(const f16x8*)(o_ws + (bm + row) * CDIM + c * 8);
        *(f16x8*)&a_lds[row * 256 + ((c ^ (row & 7)) << 3)] = v;
    }
    __syncthreads();

    const int lane = tid & 63, wv = tid >> 6;
    const int l15 = lane & 15, g = lane >> 4;
    const int m0 = (wv & 1) * 32, n0 = (wv >> 1) * 96;

    const f32x4 z4 = {0.f, 0.f, 0.f, 0.f};
    f32x4 acc[2][6];
    #pragma unroll
    for (int mi = 0; mi < 2; mi++)
        #pragma unroll
        for (int ni = 0; ni < 6; ni++) acc[mi][ni] = z4;

    #pragma unroll
    for (int kk = 0; kk < 6; kk++) {
        f16x8 af[2];
        #pragma unroll
        for (int mi = 0; mi < 2; mi++) {
            int row = m0 + mi * 16 + l15;
            af[mi] = *(const f16x8*)&a_lds[row * 256 + (((kk * 4 + g) ^ (row & 7)) << 3)];
        }
        #pragma unroll
        for (int ni = 0; ni < 6; ni++) {
            const f16x8 bf = *(const f16x8*)&wp[(n0 + ni * 16 + l15) * CDIM + kk * 32 + g * 8];
            #pragma unroll
            for (int mi = 0; mi < 2; mi++)
                acc[mi][ni] = MFMA16(af[mi], bf, acc[mi][ni]);
        }
    }

    #pragma unroll
    for (int mi = 0; mi < 2; mi++) {
        const int tok0 = bm + m0 + mi * 16 + g * 4;
        #pragma unroll
        for (int j = 0; j < 4; j++) {
            const int tok = tok0 + j;
            const int win = tok / NTOK, nloc = tok - win * NTOK;
            const int td = nloc / 49, r2 = nloc - td * 49, th = r2 / 7, tw = r2 - th * 7;
            const int wd = win >> 6, wh = (win >> 3) & 7, ww = win & 7;
            const int d = (wd * 8 + td + 4) & 15;
            int hh = wh * 7 + th + 3; if (hh >= 56) hh -= 56;
            int wco = ww * 7 + tw + 3; if (wco >= 56) wco -= 56;
            float* dst = out + ((d * 56 + hh) * 56 + wco) * CDIM;
            #pragma unroll
            for (int ni = 0; ni < 6; ni++) {
                const int n = n0 + ni * 16 + l15;
                dst[n] = acc[mi][ni][j] + bp[n];
            }
        }
    }
}

// ---------------- launch ----------------
extern "C" void kernel_launch(void* const* d_in, const int* in_sizes, int n_in,
                              void* d_out, int out_size, void* d_ws, size_t ws_size,
                              hipStream_t stream) {
    const float* x     = (const float*)d_in[0];
    const float* wqkv  = (const float*)d_in[1];
    const float* bqkv  = (const float*)d_in[2];
    const float* wproj = (const float*)d_in[3];
    const float* bproj = (const float*)d_in[4];
    const float* rtbl  = (const float*)d_in[5];
    float* out = (float*)d_out;

    // workspace layout (needs ~81.3 MB)
    const size_t QKV_BYTES = (size_t)NWIN * HEADS * NTOK * 32 * sizeof(f16);  // 19,267,584
    char* ws = (char*)d_ws;
    f16*   q_ws  = (f16*)(ws);
    f16*   k_ws  = (f16*)(ws + QKV_BYTES);
    f16*   v_ws  = (f16*)(ws + 2 * QKV_BYTES);
    f16*   o_ws  = (f16*)(ws + 3 * QKV_BYTES);
    float* rpb   = (float*)(ws + 4 * QKV_BYTES);                 // 6*400*400*4 = 3,840,000
    f16*   wq_h  = (f16*)(ws + 4 * QKV_BYTES + 3840000);         // 221,184
    f16*   wp_h  = (f16*)(ws + 4 * QKV_BYTES + 3840000 + 221184);

    wconv_kernel<<<432, 256, 0, stream>>>(wqkv, wproj, wq_h, wp_h);
    rpb_kernel<<<3750, 256, 0, stream>>>(rtbl, rpb);
    qkv_kernel<<<dim3(784, 3), 256, 0, stream>>>(x, wq_h, bqkv, q_ws, k_ws, v_ws);
    attn_kernel<<<768, 256, 0, stream>>>(q_ws, k_ws, v_ws, rpb, o_ws);
    proj_kernel<<<784, 256, 0, stream>>>(o_ws, wp_h, bproj, out);
}